// Round 7
// baseline (300.007 us; speedup 1.0000x reference)
//
#include <hip/hip_runtime.h>

// EdgeMLP: f = (relu(x@W1+b1)@W2+b2) for both edge sets, then masked pairwise
// cosine similarity out[i][j] = (cls1[i]==cls2[j]) * dot(f1_hat[i], f2_hat[j]).
// Stage 1: normalized features (bf16) + int labels into ws.
// Stage 2: EXACT R0 pair structure (best measured: residual 115.0 us) —
// non-swapped mfma_f32_16x16x32_bf16, 4 scalar strided dword stores per tile
// (4 row-segments per store instruction; A/B matrix R0/R3/R4 vs R5/R6 shows
// >=16-segment store instructions cost ~8%, <=4-segment forms all tie).
// Only change vs R0: unroll 4 -> 8 on the tile loop (deeper load pipeline to
// hide L2-hit latency on afrag/c2 loads) + vectorized mlp stores (R4-verified).

typedef __bf16 bf16x8 __attribute__((ext_vector_type(8)));
typedef float floatx4 __attribute__((ext_vector_type(4)));

__global__ __launch_bounds__(64) void mlp_norm_kernel(
    const float* __restrict__ e1, const float* __restrict__ e2,
    const float* __restrict__ W1, const float* __restrict__ b1,
    const float* __restrict__ W2, const float* __restrict__ b2,
    __bf16* __restrict__ f1b, __bf16* __restrict__ f2b,
    int* __restrict__ cls1, int* __restrict__ cls2, int N1, int N2)
{
    __shared__ __align__(16) float sW1[192];
    __shared__ float sb1[64];
    __shared__ __align__(16) float sW2[2048];
    __shared__ float sb2[32];
    for (int i = threadIdx.x; i < 192; i += 64) sW1[i] = W1[i];
    sb1[threadIdx.x] = b1[threadIdx.x];
    for (int i = threadIdx.x; i < 2048; i += 64) sW2[i] = W2[i];
    if (threadIdx.x < 32) sb2[threadIdx.x] = b2[threadIdx.x];
    __syncthreads();

    int t = blockIdx.x * 64 + threadIdx.x;
    if (t >= N1 + N2) return;

    const float* src;
    __bf16* fout;
    int* cout;
    int row;
    if (t < N1) { row = t;      src = e1 + (size_t)row * 4; fout = f1b; cout = cls1; }
    else        { row = t - N1; src = e2 + (size_t)row * 4; fout = f2b; cout = cls2; }

    float x0 = src[0], x1 = src[1], x2 = src[2];
    int lbl = (int)src[3];

    float f[32];
#pragma unroll
    for (int k = 0; k < 32; ++k) f[k] = sb2[k];

#pragma unroll 4
    for (int j = 0; j < 64; ++j) {
        float h = fmaf(x0, sW1[j], fmaf(x1, sW1[64 + j], fmaf(x2, sW1[128 + j], sb1[j])));
        h = fmaxf(h, 0.0f);
        const floatx4* w2 = (const floatx4*)(sW2 + j * 32);
#pragma unroll
        for (int k4 = 0; k4 < 8; ++k4) {
            floatx4 w = w2[k4];
            f[k4 * 4 + 0] = fmaf(h, w[0], f[k4 * 4 + 0]);
            f[k4 * 4 + 1] = fmaf(h, w[1], f[k4 * 4 + 1]);
            f[k4 * 4 + 2] = fmaf(h, w[2], f[k4 * 4 + 2]);
            f[k4 * 4 + 3] = fmaf(h, w[3], f[k4 * 4 + 3]);
        }
    }

    float ss = 0.0f;
#pragma unroll
    for (int k = 0; k < 32; ++k) ss = fmaf(f[k], f[k], ss);
    float n = sqrtf(ss);
    float scale = (n > 1e-20f) ? (1.0f / n) : 0.0f;

    // vectorized bf16 stores: 4 x 16B instead of 32 x 2B
    __bf16* dst = fout + (size_t)row * 32;
#pragma unroll
    for (int k8 = 0; k8 < 4; ++k8) {
        bf16x8 o;
#pragma unroll
        for (int k = 0; k < 8; ++k) o[k] = (__bf16)(f[k8 * 8 + k] * scale);
        *(bf16x8*)(dst + k8 * 8) = o;
    }
    cout[row] = lbl;
}

// Each wave: one 16-row strip x 512-col span (32 tiles of 16x16, one MFMA each).
// A/B fragment layout (verified R0): row = lane&15, k = (lane>>4)*8 + j
// -> both fragments are single 16B loads from the [N,32] bf16 feature arrays.
// C/D layout: col = lane&15 (output col offset r16), row = (lane>>4)*4 + reg
// (output row offset) -> 4 scalar stores at stride N2, 4 row-segments/instr.
__global__ __launch_bounds__(256) void pair_cos_kernel(
    const __bf16* __restrict__ f1b, const __bf16* __restrict__ f2b,
    const int* __restrict__ cls1, const int* __restrict__ cls2,
    float* __restrict__ out, int N2, int ncg)
{
    const int lane = threadIdx.x & 63;
    const int wid = blockIdx.x * 4 + (threadIdx.x >> 6);
    const int istrip = wid / ncg;
    const int cg = wid - istrip * ncg;
    const int i0 = istrip * 16;
    const int j0 = cg * 512;
    const int r16 = lane & 15;
    const int q = lane >> 4;

    bf16x8 a = *(const bf16x8*)(f1b + (size_t)(i0 + r16) * 32 + q * 8);
    int4 c1 = *(const int4*)(cls1 + i0 + q * 4);

    const size_t row_base = (size_t)(i0 + q * 4) * N2;

#pragma unroll 8
    for (int tIdx = 0; tIdx < 32; ++tIdx) {
        int j = j0 + tIdx * 16;
        bf16x8 b = *(const bf16x8*)(f2b + (size_t)(j + r16) * 32 + q * 8);
        int c2 = cls2[j + r16];

        floatx4 acc = {0.0f, 0.0f, 0.0f, 0.0f};
        floatx4 d = __builtin_amdgcn_mfma_f32_16x16x32_bf16(a, b, acc, 0, 0, 0);

        float* outp = out + row_base + j + r16;
        outp[0]            = (c1.x == c2) ? d[0] : 0.0f;
        outp[(size_t)N2]   = (c1.y == c2) ? d[1] : 0.0f;
        outp[(size_t)N2*2] = (c1.z == c2) ? d[2] : 0.0f;
        outp[(size_t)N2*3] = (c1.w == c2) ? d[3] : 0.0f;
    }
}

extern "C" void kernel_launch(void* const* d_in, const int* in_sizes, int n_in,
                              void* d_out, int out_size, void* d_ws, size_t ws_size,
                              hipStream_t stream) {
    const float* e1 = (const float*)d_in[0];
    const float* e2 = (const float*)d_in[1];
    const float* W1 = (const float*)d_in[2];
    const float* b1 = (const float*)d_in[3];
    const float* W2 = (const float*)d_in[4];
    const float* b2 = (const float*)d_in[5];
    float* out = (float*)d_out;

    const int N1 = in_sizes[0] / 4;  // 8192
    const int N2 = in_sizes[1] / 4;  // 8192

    char* ws = (char*)d_ws;
    __bf16* f1b = (__bf16*)ws;                                   // N1*32 bf16
    __bf16* f2b = (__bf16*)(ws + (size_t)N1 * 64);               // N2*32 bf16
    int* cls1 = (int*)(ws + (size_t)(N1 + N2) * 64);             // N1 ints
    int* cls2 = cls1 + N1;                                       // N2 ints

    int nrows = N1 + N2;
    mlp_norm_kernel<<<(nrows + 63) / 64, 64, 0, stream>>>(
        e1, e2, W1, b1, W2, b2, f1b, f2b, cls1, cls2, N1, N2);

    int ncg = N2 / 512;                 // 16 col-groups of 512
    int nwaves = (N1 / 16) * ncg;       // 8192 waves
    pair_cos_kernel<<<nwaves / 4, 256, 0, stream>>>(
        f1b, f2b, cls1, cls2, out, N2, ncg);
}

// Round 8
// 278.698 us; speedup vs baseline: 1.0765x; 1.0765x over previous
//
#include <hip/hip_runtime.h>

// EdgeMLP: f = (relu(x@W1+b1)@W2+b2) for both edge sets, then masked pairwise
// cosine similarity out[i][j] = (cls1[i]==cls2[j]) * dot(f1_hat[i], f2_hat[j]).
// Stage 1: normalized features (bf16) + int labels into ws (exact R0 version).
// Stage 2 v5: 32x32x16 MFMA pair kernel. C/D layout (HW-verified m74/m101):
// col = lane&31, row = (reg&3) + 8*(reg>>2) + 4*(lane>>5), reg in [0,16).
// Every scalar store instruction covers 2 FULL 128B-aligned L2 lines
// (32 lanes x 4B consecutive per row, 2 rows) vs 4x64B partial segments in
// the 16x16 form -- tests the partial-line-write-overhead theory for the
// ~20us gap between pair (~65us) and its 41us write floor. Also 2 MFMAs per
// 32x32 tile instead of 4. Grid shape identical to R0 (8192 waves).

typedef __bf16 bf16x8 __attribute__((ext_vector_type(8)));
typedef float floatx16 __attribute__((ext_vector_type(16)));

__global__ __launch_bounds__(256) void mlp_norm_kernel(
    const float* __restrict__ e1, const float* __restrict__ e2,
    const float* __restrict__ W1, const float* __restrict__ b1,
    const float* __restrict__ W2, const float* __restrict__ b2,
    __bf16* __restrict__ f1b, __bf16* __restrict__ f2b,
    int* __restrict__ cls1, int* __restrict__ cls2, int N1, int N2)
{
    __shared__ float sW1[192];
    __shared__ float sb1[64];
    __shared__ float sW2[2048];
    __shared__ float sb2[32];
    for (int i = threadIdx.x; i < 192; i += 256) sW1[i] = W1[i];
    if (threadIdx.x < 64) sb1[threadIdx.x] = b1[threadIdx.x];
    for (int i = threadIdx.x; i < 2048; i += 256) sW2[i] = W2[i];
    if (threadIdx.x < 32) sb2[threadIdx.x] = b2[threadIdx.x];
    __syncthreads();

    int t = blockIdx.x * 256 + threadIdx.x;
    if (t >= N1 + N2) return;

    const float* src;
    __bf16* fout;
    int* cout;
    int row;
    if (t < N1) { row = t;      src = e1 + (size_t)row * 4; fout = f1b; cout = cls1; }
    else        { row = t - N1; src = e2 + (size_t)row * 4; fout = f2b; cout = cls2; }

    float x0 = src[0], x1 = src[1], x2 = src[2];
    int lbl = (int)src[3];

    float f[32];
#pragma unroll
    for (int k = 0; k < 32; ++k) f[k] = sb2[k];

    for (int j = 0; j < 64; ++j) {
        float h = fmaf(x0, sW1[j], fmaf(x1, sW1[64 + j], fmaf(x2, sW1[128 + j], sb1[j])));
        h = fmaxf(h, 0.0f);
#pragma unroll
        for (int k = 0; k < 32; ++k) f[k] = fmaf(h, sW2[j * 32 + k], f[k]);
    }

    float ss = 0.0f;
#pragma unroll
    for (int k = 0; k < 32; ++k) ss = fmaf(f[k], f[k], ss);
    float n = sqrtf(ss);
    float scale = (n > 1e-20f) ? (1.0f / n) : 0.0f;

    __bf16* dst = fout + (size_t)row * 32;
#pragma unroll
    for (int k = 0; k < 32; ++k) dst[k] = (__bf16)(f[k] * scale);
    cout[row] = lbl;
}

// Each wave: one 32-row strip x 256-col span (8 tiles of 32x32, 2 MFMAs each).
// A/B fragment layout (32x32x16): row = lane&31, k = (lane>>5)*8 + j.
// Feature dim 32 = two K=16 steps -> two chained MFMAs accumulate.
// C/D: col = lane&31, row = (reg&3) + 8*(reg>>2) + 4*(lane>>5).
__global__ __launch_bounds__(256) void pair_cos_kernel(
    const __bf16* __restrict__ f1b, const __bf16* __restrict__ f2b,
    const int* __restrict__ cls1, const int* __restrict__ cls2,
    float* __restrict__ out, int N2, int ncg)
{
    const int lane = threadIdx.x & 63;
    const int wid = blockIdx.x * 4 + (threadIdx.x >> 6);
    const int istrip = wid / ncg;
    const int cg = wid - istrip * ncg;
    const int i0 = istrip * 32;
    const int j0 = cg * 256;
    const int r32 = lane & 31;
    const int hi = lane >> 5;              // 0 or 1

    // A fragments: f1 rows i0..i0+31; k-halves 0..15 and 16..31.
    const __bf16* arow = f1b + (size_t)(i0 + r32) * 32 + hi * 8;
    bf16x8 a0 = *(const bf16x8*)(arow);
    bf16x8 a1 = *(const bf16x8*)(arow + 16);

    // cls1 for this lane's 16 store rows: row = i0 + 8g + 4*hi + r, r=0..3.
    int4 c1g0 = *(const int4*)(cls1 + i0 + 4 * hi);
    int4 c1g1 = *(const int4*)(cls1 + i0 + 8 + 4 * hi);
    int4 c1g2 = *(const int4*)(cls1 + i0 + 16 + 4 * hi);
    int4 c1g3 = *(const int4*)(cls1 + i0 + 24 + 4 * hi);

    float* obase = out + (size_t)(i0 + 4 * hi) * N2 + r32;

#pragma unroll 2
    for (int t = 0; t < 8; ++t) {
        const int j = j0 + t * 32;
        const __bf16* brow = f2b + (size_t)(j + r32) * 32 + hi * 8;
        bf16x8 b0 = *(const bf16x8*)(brow);
        bf16x8 b1 = *(const bf16x8*)(brow + 16);
        const int c2 = cls2[j + r32];

        floatx16 acc = {};
        acc = __builtin_amdgcn_mfma_f32_32x32x16_bf16(a0, b0, acc, 0, 0, 0);
        acc = __builtin_amdgcn_mfma_f32_32x32x16_bf16(a1, b1, acc, 0, 0, 0);

        float* outp = obase + j;
        // g-group 0: rows +0..3
        outp[(size_t)0 * N2] = (c1g0.x == c2) ? acc[0] : 0.0f;
        outp[(size_t)1 * N2] = (c1g0.y == c2) ? acc[1] : 0.0f;
        outp[(size_t)2 * N2] = (c1g0.z == c2) ? acc[2] : 0.0f;
        outp[(size_t)3 * N2] = (c1g0.w == c2) ? acc[3] : 0.0f;
        // g-group 1: rows +8..11
        outp[(size_t)8 * N2]  = (c1g1.x == c2) ? acc[4] : 0.0f;
        outp[(size_t)9 * N2]  = (c1g1.y == c2) ? acc[5] : 0.0f;
        outp[(size_t)10 * N2] = (c1g1.z == c2) ? acc[6] : 0.0f;
        outp[(size_t)11 * N2] = (c1g1.w == c2) ? acc[7] : 0.0f;
        // g-group 2: rows +16..19
        outp[(size_t)16 * N2] = (c1g2.x == c2) ? acc[8] : 0.0f;
        outp[(size_t)17 * N2] = (c1g2.y == c2) ? acc[9] : 0.0f;
        outp[(size_t)18 * N2] = (c1g2.z == c2) ? acc[10] : 0.0f;
        outp[(size_t)19 * N2] = (c1g2.w == c2) ? acc[11] : 0.0f;
        // g-group 3: rows +24..27
        outp[(size_t)24 * N2] = (c1g3.x == c2) ? acc[12] : 0.0f;
        outp[(size_t)25 * N2] = (c1g3.y == c2) ? acc[13] : 0.0f;
        outp[(size_t)26 * N2] = (c1g3.z == c2) ? acc[14] : 0.0f;
        outp[(size_t)27 * N2] = (c1g3.w == c2) ? acc[15] : 0.0f;
    }
}

extern "C" void kernel_launch(void* const* d_in, const int* in_sizes, int n_in,
                              void* d_out, int out_size, void* d_ws, size_t ws_size,
                              hipStream_t stream) {
    const float* e1 = (const float*)d_in[0];
    const float* e2 = (const float*)d_in[1];
    const float* W1 = (const float*)d_in[2];
    const float* b1 = (const float*)d_in[3];
    const float* W2 = (const float*)d_in[4];
    const float* b2 = (const float*)d_in[5];
    float* out = (float*)d_out;

    const int N1 = in_sizes[0] / 4;  // 8192
    const int N2 = in_sizes[1] / 4;  // 8192

    char* ws = (char*)d_ws;
    __bf16* f1b = (__bf16*)ws;                                   // N1*32 bf16
    __bf16* f2b = (__bf16*)(ws + (size_t)N1 * 64);               // N2*32 bf16
    int* cls1 = (int*)(ws + (size_t)(N1 + N2) * 64);             // N1 ints
    int* cls2 = cls1 + N1;                                       // N2 ints

    int nrows = N1 + N2;
    mlp_norm_kernel<<<(nrows + 255) / 256, 256, 0, stream>>>(
        e1, e2, W1, b1, W2, b2, f1b, f2b, cls1, cls2, N1, N2);

    int ncg = N2 / 256;                 // 32 col-groups of 256
    int nwaves = (N1 / 32) * ncg;       // 8192 waves
    pair_cos_kernel<<<nwaves / 4, 256, 0, stream>>>(
        f1b, f2b, cls1, cls2, out, N2, ncg);
}